// Round 1
// baseline (1605.137 us; speedup 1.0000x reference)
//
#include <hip/hip_runtime.h>
#include <math.h>

typedef unsigned short u16;
typedef __attribute__((ext_vector_type(8))) short bf16x8;   // 8 x bf16 (4 VGPRs)
typedef __attribute__((ext_vector_type(4))) float f32x4;    // MFMA C/D

#define NROI 2048
#define DDIM 2048

__device__ __forceinline__ float bf2f(u16 h) {
    union { unsigned u; float f; } c; c.u = ((unsigned)h) << 16; return c.f;
}
__device__ __forceinline__ u16 f2bf(float f) {
    union { float f; unsigned u; } c; c.f = f;
    unsigned u = c.u;
    return (u16)((u + 0x7fffu + ((u >> 16) & 1u)) >> 16);   // RNE
}

// ---- dtype probe: bf16 halfwords of N(0,1) data have exponent ~127; fp32 low
// halfwords are uniform bits. Counts plausible-exponent hits on even u16s.
__global__ void detect_k(const u16* __restrict__ x, int* flag) {
    if (blockIdx.x == 0 && threadIdx.x == 0) {
        int hits = 0;
        for (int i = 0; i < 2048; i += 2) {
            int e = (x[i] >> 7) & 0xFF;
            if (e >= 100 && e <= 131) hits++;
        }
        *flag = (hits > 512) ? 1 : 0;   // 1 => bf16 storage
    }
}

// ---- canonicalize a float tensor (bf16-or-fp32 storage) to bf16
__global__ __launch_bounds__(256) void conv_k(const void* __restrict__ src,
                                              u16* __restrict__ dst, int n,
                                              const int* __restrict__ flag) {
    int i = blockIdx.x * 256 + threadIdx.x;
    if (i >= n) return;
    if (*flag) dst[i] = ((const u16*)src)[i];
    else       dst[i] = f2bf(((const float*)src)[i]);
}

// ---- avgpool 7x7 -> fp32 master + bf16 shadow
__global__ __launch_bounds__(256) void pool_k(const void* __restrict__ xin,
                                              float* __restrict__ xf, u16* __restrict__ xb,
                                              const int* __restrict__ flag) {
    int idx = blockIdx.x * 256 + threadIdx.x;   // one (n,d) pair per thread
    float s = 0.f;
    if (*flag) {
        const u16* p = (const u16*)xin + (size_t)idx * 49;
        #pragma unroll
        for (int i = 0; i < 49; ++i) s += bf2f(p[i]);
    } else {
        const float* p = (const float*)xin + (size_t)idx * 49;
        #pragma unroll
        for (int i = 0; i < 49; ++i) s += p[i];
    }
    float m = s * (1.0f / 49.0f);
    xf[idx] = m;
    xb[idx] = f2bf(m);
}

// ---- row L2 norms of fp32 [2048,2048]
__global__ __launch_bounds__(256) void norms_k(const float* __restrict__ xf,
                                               float* __restrict__ nrm) {
    int row = blockIdx.x;
    const float* p = xf + (size_t)row * DDIM;
    float s = 0.f;
    for (int i = threadIdx.x; i < DDIM; i += 256) { float v = p[i]; s += v * v; }
    for (int o = 32; o > 0; o >>= 1) s += __shfl_down(s, o);
    __shared__ float red[4];
    if ((threadIdx.x & 63) == 0) red[threadIdx.x >> 6] = s;
    __syncthreads();
    if (threadIdx.x == 0) nrm[row] = sqrtf(red[0] + red[1] + red[2] + red[3]);
}

// ---- bf16 2048x2048 transpose (32x33 LDS tile)
__global__ __launch_bounds__(256) void transpose_k(const u16* __restrict__ in,
                                                   u16* __restrict__ out) {
    __shared__ u16 tile[32][33];
    int c0 = blockIdx.x * 32, r0 = blockIdx.y * 32;
    int lx = threadIdx.x & 31, ly = threadIdx.x >> 5;   // ly in 0..7
    #pragma unroll
    for (int i = 0; i < 32; i += 8)
        tile[ly + i][lx] = in[(size_t)(r0 + ly + i) * DDIM + c0 + lx];
    __syncthreads();
    #pragma unroll
    for (int i = 0; i < 32; i += 8)
        out[(size_t)(c0 + ly + i) * DDIM + r0 + lx] = tile[lx][ly + i];
}

// ---- row softmax fp32 [2048,2048] -> bf16
__global__ __launch_bounds__(256) void softmax_k(const float* __restrict__ s,
                                                 u16* __restrict__ p) {
    int row = blockIdx.x;
    const float* sr = s + (size_t)row * DDIM;
    float v[8];
    float mx = -3e38f;
    #pragma unroll
    for (int j = 0; j < 8; ++j) { v[j] = sr[threadIdx.x + j * 256]; mx = fmaxf(mx, v[j]); }
    for (int o = 32; o > 0; o >>= 1) mx = fmaxf(mx, __shfl_down(mx, o));
    __shared__ float redm[4];
    if ((threadIdx.x & 63) == 0) redm[threadIdx.x >> 6] = mx;
    __syncthreads();
    mx = fmaxf(fmaxf(redm[0], redm[1]), fmaxf(redm[2], redm[3]));
    float sum = 0.f;
    #pragma unroll
    for (int j = 0; j < 8; ++j) { v[j] = expf(v[j] - mx); sum += v[j]; }
    for (int o = 32; o > 0; o >>= 1) sum += __shfl_down(sum, o);
    __shared__ float reds[4];
    if ((threadIdx.x & 63) == 0) reds[threadIdx.x >> 6] = sum;
    __syncthreads();
    sum = reds[0] + reds[1] + reds[2] + reds[3];
    float inv = 1.0f / sum;
    #pragma unroll
    for (int j = 0; j < 8; ++j)
        p[(size_t)row * DDIM + threadIdx.x + j * 256] = f2bf(v[j] * inv);
}

// ---- MFMA GEMM: C[M,Nc] = A[M,K] * Bt[Nc,K]^T, bf16 operands, fp32 accum.
// MODE 0: graph epilogue  -> outB = bf16( C / max(nrm[i]*nrm[j], eps) )
// MODE 1: plain           -> outF = C
// MODE 2: linear+residual -> v = C + bias[col] + res;  outF = v; outB = bf16(v)
// Tile 128x128, BK=32; 4 waves in 2x2, each wave 4x4 grid of 16x16x32 MFMAs.
// Verified layouts (learn_hip m89/m91): A/B frag [lane&15][quad*8+j];
// C/D: row = quad*4 + r, col = lane&15.
template <int MODE>
__global__ __launch_bounds__(256) void gemm_bt(
    const u16* __restrict__ A, const u16* __restrict__ Bt,
    int M, int Nc, int K,
    float* __restrict__ outF, u16* __restrict__ outB,
    const float* __restrict__ nrm, const u16* __restrict__ bias,
    const float* __restrict__ res) {
    __shared__ u16 As[128 * 32];
    __shared__ u16 Bs[128 * 32];
    const int t = threadIdx.x;
    const int lane = t & 63, wave = t >> 6;
    const int quad = lane >> 4, l16 = lane & 15;
    const int wr = (wave >> 1) * 64;
    const int wc = (wave & 1) * 64;
    const int bm = blockIdx.y * 128;
    const int bn = blockIdx.x * 128;
    const int row = t >> 2;            // 0..63
    const int cg = (t & 3) * 8;        // k offset within BK, elements

    f32x4 zero = {0.f, 0.f, 0.f, 0.f};
    f32x4 acc[4][4];
    #pragma unroll
    for (int i = 0; i < 4; ++i)
        #pragma unroll
        for (int j = 0; j < 4; ++j) acc[i][j] = zero;

    for (int k0 = 0; k0 < K; k0 += 32) {
        uint4 a0 = *(const uint4*)(A + (size_t)(bm + row) * K + k0 + cg);
        uint4 a1 = *(const uint4*)(A + (size_t)(bm + row + 64) * K + k0 + cg);
        uint4 b0 = *(const uint4*)(Bt + (size_t)(bn + row) * K + k0 + cg);
        uint4 b1 = *(const uint4*)(Bt + (size_t)(bn + row + 64) * K + k0 + cg);
        __syncthreads();                       // prev-iter LDS reads done
        *(uint4*)&As[row * 32 + cg] = a0;
        *(uint4*)&As[(row + 64) * 32 + cg] = a1;
        *(uint4*)&Bs[row * 32 + cg] = b0;
        *(uint4*)&Bs[(row + 64) * 32 + cg] = b1;
        __syncthreads();
        bf16x8 af[4], bfr[4];
        #pragma unroll
        for (int ms = 0; ms < 4; ++ms)
            af[ms] = *(const bf16x8*)&As[(wr + ms * 16 + l16) * 32 + quad * 8];
        #pragma unroll
        for (int ns = 0; ns < 4; ++ns)
            bfr[ns] = *(const bf16x8*)&Bs[(wc + ns * 16 + l16) * 32 + quad * 8];
        #pragma unroll
        for (int ms = 0; ms < 4; ++ms)
            #pragma unroll
            for (int ns = 0; ns < 4; ++ns)
                acc[ms][ns] = __builtin_amdgcn_mfma_f32_16x16x32_bf16(
                    af[ms], bfr[ns], acc[ms][ns], 0, 0, 0);
    }

    #pragma unroll
    for (int ms = 0; ms < 4; ++ms) {
        int grow_base = bm + wr + ms * 16 + quad * 4;
        #pragma unroll
        for (int ns = 0; ns < 4; ++ns) {
            int gcol = bn + wc + ns * 16 + l16;
            #pragma unroll
            for (int r = 0; r < 4; ++r) {
                int grow = grow_base + r;
                float v = acc[ms][ns][r];
                size_t o = (size_t)grow * Nc + gcol;
                if (MODE == 0) {
                    float dn = fmaxf(nrm[grow] * nrm[gcol], 1e-8f);
                    outB[o] = f2bf(v / dn);
                } else if (MODE == 1) {
                    outF[o] = v;
                } else {
                    v += bf2f(bias[gcol]) + res[o];
                    outF[o] = v;
                    outB[o] = f2bf(v);
                }
            }
        }
    }
}

// ---- classification/bbox heads: [2048,2048] fp32 x bf16 W^T, bf16/fp32 out
__global__ __launch_bounds__(256) void heads_k(const float* __restrict__ x,
                                               const u16* __restrict__ Wc, const u16* __restrict__ bc,
                                               const u16* __restrict__ Wb, const u16* __restrict__ bb,
                                               void* __restrict__ out, const int* __restrict__ flag) {
    __shared__ float xr[DDIM];
    int i = blockIdx.x;
    for (int k = threadIdx.x; k < DDIM; k += 256) xr[k] = x[(size_t)i * DDIM + k];
    __syncthreads();
    int wave = threadIdx.x >> 6, lane = threadIdx.x & 63;
    int obf = *flag;
    for (int c = wave; c < 45; c += 4) {
        const u16* Wrow = (c < 9) ? (Wc + (size_t)c * DDIM) : (Wb + (size_t)(c - 9) * DDIM);
        float s = 0.f;
        for (int k = lane; k < DDIM; k += 64) s += xr[k] * bf2f(Wrow[k]);
        for (int o = 32; o > 0; o >>= 1) s += __shfl_down(s, o);
        if (lane == 0) {
            float v = s + bf2f((c < 9) ? bc[c] : bb[c - 9]);
            size_t oidx = (c < 9) ? ((size_t)i * 9 + c)
                                  : (size_t)(2048 * 9) + (size_t)i * 36 + (c - 9);
            if (obf) ((u16*)out)[oidx] = f2bf(v);
            else     ((float*)out)[oidx] = v;
        }
    }
}

extern "C" void kernel_launch(void* const* d_in, const int* in_sizes, int n_in,
                              void* d_out, int out_size, void* d_ws, size_t ws_size,
                              hipStream_t stream) {
    const void* x_raw  = d_in[0];
    const void* Wt_raw = d_in[1]; const void* bt_raw = d_in[2];
    const void* Wr_raw = d_in[3]; const void* br_raw = d_in[4];
    const void* Wc_raw = d_in[5]; const void* bc_raw = d_in[6];
    const void* Wb_raw = d_in[7]; const void* bb_raw = d_in[8];

    char* w = (char*)d_ws;
    const size_t MB = 1u << 20;
    float* x0f  = (float*)(w);                    // 16 MB   pooled x (fp32 master) / later x2
    float* x1f  = (float*)(w + 16 * MB);          // 16 MB   stage-1 result (fp32 master)
    float* s_f  = (float*)(w + 32 * MB);          // 16 MB   mat@x logits
    u16*   x0b  = (u16*)(w + 48 * MB);            //  8 MB   bf16 shadow of current x
    u16*   xTb  = (u16*)(w + 56 * MB);            //  8 MB   bf16 x^T
    u16*   matb = (u16*)(w + 64 * MB);            //  8 MB   graph matrix, then softmax P
    u16*   Wt_c = (u16*)(w + 72 * MB);            //  8 MB   canonical bf16 weights
    u16*   Wr_c = (u16*)(w + 80 * MB);            //  8 MB
    u16*   Wc_c = (u16*)(w + 88 * MB);            //  36 KB
    u16*   Wb_c = (u16*)(w + 88 * MB + 256 * 1024); // 147 KB
    u16*   bt_c = (u16*)(w + 88 * MB + 512 * 1024);
    u16*   br_c = (u16*)(w + 88 * MB + 576 * 1024);
    u16*   bc_c = (u16*)(w + 88 * MB + 640 * 1024);
    u16*   bb_c = (u16*)(w + 88 * MB + 704 * 1024);
    float* nrm  = (float*)(w + 89 * MB);          // 8 KB
    int*   flag = (int*)(w + 89 * MB + 64 * 1024);

    (void)in_sizes; (void)n_in; (void)out_size; (void)ws_size;

    // dtype probe + canonicalization
    detect_k<<<1, 64, 0, stream>>>((const u16*)x_raw, flag);
    conv_k<<<16384, 256, 0, stream>>>(Wt_raw, Wt_c, 2048 * 2048, flag);
    conv_k<<<16384, 256, 0, stream>>>(Wr_raw, Wr_c, 2048 * 2048, flag);
    conv_k<<<72, 256, 0, stream>>>(Wc_raw, Wc_c, 9 * 2048, flag);
    conv_k<<<288, 256, 0, stream>>>(Wb_raw, Wb_c, 36 * 2048, flag);
    conv_k<<<8, 256, 0, stream>>>(bt_raw, bt_c, 2048, flag);
    conv_k<<<8, 256, 0, stream>>>(br_raw, br_c, 2048, flag);
    conv_k<<<1, 256, 0, stream>>>(bc_raw, bc_c, 9, flag);
    conv_k<<<1, 256, 0, stream>>>(bb_raw, bb_c, 36, flag);

    dim3 g16(16, 16);

    // stage 0: pool
    pool_k<<<16384, 256, 0, stream>>>(x_raw, x0f, x0b, flag);

    // stage 1
    norms_k<<<2048, 256, 0, stream>>>(x0f, nrm);
    transpose_k<<<dim3(64, 64), 256, 0, stream>>>(x0b, xTb);
    gemm_bt<0><<<g16, 256, 0, stream>>>(x0b, x0b, 2048, 2048, 2048,
                                        nullptr, matb, nrm, nullptr, nullptr);
    gemm_bt<1><<<g16, 256, 0, stream>>>(matb, xTb, 2048, 2048, 2048,
                                        s_f, nullptr, nullptr, nullptr, nullptr);
    softmax_k<<<2048, 256, 0, stream>>>(s_f, matb);          // matb := P
    gemm_bt<2><<<g16, 256, 0, stream>>>(matb, Wt_c, 2048, 2048, 2048,
                                        x1f, x0b, nullptr, bt_c, x0f);  // x1 = P@Wt^T + b + x0

    // stage 2
    norms_k<<<2048, 256, 0, stream>>>(x1f, nrm);
    transpose_k<<<dim3(64, 64), 256, 0, stream>>>(x0b, xTb); // x0b now holds bf16(x1)
    gemm_bt<0><<<g16, 256, 0, stream>>>(x0b, x0b, 2048, 2048, 2048,
                                        nullptr, matb, nrm, nullptr, nullptr);
    gemm_bt<1><<<g16, 256, 0, stream>>>(matb, xTb, 2048, 2048, 2048,
                                        s_f, nullptr, nullptr, nullptr, nullptr);
    softmax_k<<<2048, 256, 0, stream>>>(s_f, matb);          // matb := P2
    gemm_bt<2><<<g16, 256, 0, stream>>>(matb, Wr_c, 2048, 2048, 2048,
                                        x0f, x0b, nullptr, br_c, x1f);  // x2 = P2@Wr^T + b + x1

    // heads
    heads_k<<<2048, 256, 0, stream>>>(x0f, Wc_c, bc_c, Wb_c, bb_c, d_out, flag);
}